// Round 1
// baseline (1320.390 us; speedup 1.0000x reference)
//
#include <hip/hip_runtime.h>
#include <hip/hip_bf16.h>

typedef __attribute__((ext_vector_type(8))) short short8;
typedef __attribute__((ext_vector_type(4))) float floatx4;

#define BM 256
#define BN 128
#define BK 32
#define CAP 256      // max tokens per expert (mean 128, sigma ~11 -> safe)
#define NEXP 32
#define NTOK 2048
#define DDIM 1024
#define HDIM 4096
#define HSH 2048

__device__ __forceinline__ void g2lds16(const void* g, void* l) {
  __builtin_amdgcn_global_load_lds((const __attribute__((address_space(1))) void*)g,
                                   (__attribute__((address_space(3))) void*)l, 16, 0, 0);
}

__device__ __forceinline__ short f2bf(float f) {
  union { __hip_bfloat16 h; unsigned short u; } c;
  c.h = __float2bfloat16(f);
  return (short)c.u;
}

// ---------------- gate + routing + gather ----------------
__global__ __launch_bounds__(256)
void gate_kernel(const float* __restrict__ x, const float* __restrict__ gate_w,
                 const float* __restrict__ bias,
                 __hip_bfloat16* __restrict__ xbf, __hip_bfloat16* __restrict__ Xg,
                 int* __restrict__ counts, int* __restrict__ assign_token,
                 float* __restrict__ assign_w) {
  const int wv = threadIdx.x >> 6, lane = threadIdx.x & 63;
  const int n = blockIdx.x * 4 + wv;
  const float4* xr = reinterpret_cast<const float4*>(x + (size_t)n * DDIM);
  float4 xv0 = xr[lane * 4 + 0], xv1 = xr[lane * 4 + 1];
  float4 xv2 = xr[lane * 4 + 2], xv3 = xr[lane * 4 + 3];

  float best = -1e30f, second = -1e30f; int bi = 0, si = 0;
  for (int e = 0; e < NEXP; e++) {
    const float4* gw = reinterpret_cast<const float4*>(gate_w + (size_t)e * DDIM);
    float4 g0 = gw[lane * 4 + 0], g1 = gw[lane * 4 + 1];
    float4 g2 = gw[lane * 4 + 2], g3 = gw[lane * 4 + 3];
    float s = g0.x*xv0.x + g0.y*xv0.y + g0.z*xv0.z + g0.w*xv0.w
            + g1.x*xv1.x + g1.y*xv1.y + g1.z*xv1.z + g1.w*xv1.w
            + g2.x*xv2.x + g2.y*xv2.y + g2.z*xv2.z + g2.w*xv2.w
            + g3.x*xv3.x + g3.y*xv3.y + g3.z*xv3.z + g3.w*xv3.w;
    #pragma unroll
    for (int off = 32; off > 0; off >>= 1) s += __shfl_xor(s, off);
    s = 1.f / (1.f + expf(-s)) + bias[e];
    if (s > best)        { second = best; si = bi; best = s; bi = e; }
    else if (s > second) { second = s; si = e; }
  }
  float denom = best + second + 1e-20f;
  float w0 = best / denom, w1 = second / denom;

  short8 p0, p1;
  p0[0]=f2bf(xv0.x); p0[1]=f2bf(xv0.y); p0[2]=f2bf(xv0.z); p0[3]=f2bf(xv0.w);
  p0[4]=f2bf(xv1.x); p0[5]=f2bf(xv1.y); p0[6]=f2bf(xv1.z); p0[7]=f2bf(xv1.w);
  p1[0]=f2bf(xv2.x); p1[1]=f2bf(xv2.y); p1[2]=f2bf(xv2.z); p1[3]=f2bf(xv2.w);
  p1[4]=f2bf(xv3.x); p1[5]=f2bf(xv3.y); p1[6]=f2bf(xv3.z); p1[7]=f2bf(xv3.w);

  short8* xo = (short8*)(xbf + (size_t)n * DDIM);
  xo[lane * 2] = p0; xo[lane * 2 + 1] = p1;

  int slot0 = -1, slot1 = -1;
  if (lane == 0) {
    int p = atomicAdd(&counts[bi], 1);
    if (p < CAP) slot0 = bi * CAP + p;
    p = atomicAdd(&counts[si], 1);
    if (p < CAP) slot1 = si * CAP + p;
  }
  slot0 = __shfl(slot0, 0); slot1 = __shfl(slot1, 0);
  if (slot0 >= 0) {
    if (lane == 0) { assign_token[slot0] = n; assign_w[slot0] = w0; }
    short8* o = (short8*)(Xg + (size_t)slot0 * DDIM);
    o[lane * 2] = p0; o[lane * 2 + 1] = p1;
  }
  if (slot1 >= 0) {
    if (lane == 0) { assign_token[slot1] = n; assign_w[slot1] = w1; }
    short8* o = (short8*)(Xg + (size_t)slot1 * DDIM);
    o[lane * 2] = p0; o[lane * 2 + 1] = p1;
  }
}

// ---------------- unified MFMA GEMM ----------------
// C[BM x BN] tile = A(bf16, row-major, ld=K) @ B(fp32, row-major, ld=ldB)
// EPI 0: silu -> bf16 store (ldC)    EPI 1: weighted atomicAdd via slot->token
// EPI 2: plain atomicAdd (split-K into zeroed out)
template<int EPI>
__global__ __launch_bounds__(256, 2)
void gemm_kernel(const __hip_bfloat16* __restrict__ A, size_t a_blk_stride,
                 const float* __restrict__ B, size_t b_blk_stride,
                 int K, int Ksplit, int ldB, int ldC,
                 float* __restrict__ outF, __hip_bfloat16* __restrict__ outH,
                 const int* __restrict__ assign_token,
                 const float* __restrict__ assign_w) {
  __shared__ __align__(16) __hip_bfloat16 sA[BM * BK];        // [256][32] plain
  __shared__ __align__(16) unsigned char sB[BN * 80];         // [128] rows, 80B stride, XOR-swizzled

  const int tid = threadIdx.x;
  const int wv = tid >> 6, lane = tid & 63;
  const int bx = blockIdx.x, by = blockIdx.y, bz = blockIdx.z;
  const int rl = lane & 15, qd = lane >> 4;

  const __hip_bfloat16* Ab = A + (size_t)by * a_blk_stride;
  const float* Bb = B + (size_t)by * b_blk_stride + (size_t)bx * BN;

  floatx4 acc[4][8];
  #pragma unroll
  for (int m = 0; m < 4; m++)
    #pragma unroll
    for (int ns = 0; ns < 8; ns++) acc[m][ns] = (floatx4){0.f, 0.f, 0.f, 0.f};

  const int bn0 = (tid & 31) * 4;   // B stage: col base
  const int bkq = tid >> 5;         // B stage: k-chunk (only tid<128 -> 0..3)
  const int k_begin = bz * Ksplit, k_end = k_begin + Ksplit;

  for (int k0 = k_begin; k0 < k_end; k0 += BK) {
    // -- stage A: 256x32 bf16 via async global->LDS, 16B/lane, wave-uniform base --
    #pragma unroll
    for (int i = 0; i < 4; i++) {
      int c = (i * 4 + wv) * 64 + lane;         // 16B-chunk id
      int row = c >> 2, q = c & 3;
      const __hip_bfloat16* gp = Ab + (size_t)row * K + k0 + q * 8;
      g2lds16((const void*)gp, (void*)(sA + (size_t)(i * 4 + wv) * 512));
    }
    // -- stage B: 32k x 128n fp32 -> bf16, transposed into LDS [n][k] --
    if (tid < 128) {
      const float* bp = Bb + (size_t)(k0 + bkq * 8) * ldB + bn0;
      float4 rr[8];
      #pragma unroll
      for (int j = 0; j < 8; j++) rr[j] = *(const float4*)(bp + (size_t)j * ldB);
      #pragma unroll
      for (int jj = 0; jj < 4; jj++) {
        int n = bn0 + jj;
        short8 v;
        #pragma unroll
        for (int i = 0; i < 8; i++) v[i] = f2bf(((const float*)&rr[i])[jj]);
        int qp = bkq ^ (((n >> 2) + (n >> 4)) & 3);
        *(short8*)(sB + (size_t)n * 80 + qp * 16) = v;
      }
    }
    __syncthreads();

    short8 af[4];
    #pragma unroll
    for (int m = 0; m < 4; m++) {
      int row = wv * 64 + m * 16 + rl;
      af[m] = *(const short8*)((const unsigned char*)sA + (size_t)row * 64 + qd * 16);
    }
    short8 bfr[8];
    #pragma unroll
    for (int ns = 0; ns < 8; ns++) {
      int n = ns * 16 + rl;
      int qp = qd ^ (((n >> 2) + (n >> 4)) & 3);
      bfr[ns] = *(const short8*)(sB + (size_t)n * 80 + qp * 16);
    }
    #pragma unroll
    for (int m = 0; m < 4; m++)
      #pragma unroll
      for (int ns = 0; ns < 8; ns++)
        acc[m][ns] = __builtin_amdgcn_mfma_f32_16x16x32_bf16(af[m], bfr[ns], acc[m][ns], 0, 0, 0);
    __syncthreads();
  }

  // -------- epilogue --------
  const int colbase = bx * BN;
  #pragma unroll
  for (int m = 0; m < 4; m++) {
    #pragma unroll
    for (int r = 0; r < 4; r++) {
      int row = wv * 64 + m * 16 + qd * 4 + r;
      if (EPI == 0) {
        #pragma unroll
        for (int ns = 0; ns < 8; ns++) {
          float v = acc[m][ns][r];
          float sv = v / (1.f + __expf(-v));   // silu
          outH[((size_t)by * BM + row) * ldC + colbase + ns * 16 + rl] = __float2bfloat16(sv);
        }
      } else if (EPI == 1) {
        int slot = by * BM + row;
        int tok = assign_token[slot];
        if (tok >= 0) {
          float wgt = assign_w[slot];
          #pragma unroll
          for (int ns = 0; ns < 8; ns++)
            atomicAdd(outF + (size_t)tok * ldC + colbase + ns * 16 + rl, wgt * acc[m][ns][r]);
        }
      } else {
        #pragma unroll
        for (int ns = 0; ns < 8; ns++)
          atomicAdd(outF + ((size_t)by * BM + row) * ldC + colbase + ns * 16 + rl, acc[m][ns][r]);
      }
    }
  }
}

// ---------------- launch ----------------
extern "C" void kernel_launch(void* const* d_in, const int* in_sizes, int n_in,
                              void* d_out, int out_size, void* d_ws, size_t ws_size,
                              hipStream_t stream) {
  const float* x         = (const float*)d_in[0];
  const float* gate_w    = (const float*)d_in[1];
  const float* bias      = (const float*)d_in[2];
  const float* shared_w1 = (const float*)d_in[3];
  const float* shared_w2 = (const float*)d_in[4];
  const float* expert_w1 = (const float*)d_in[5];
  const float* expert_w2 = (const float*)d_in[6];
  float* out = (float*)d_out;

  char* w = (char*)d_ws;
  int*   counts       = (int*)w;                      // 32 ints
  int*   assign_token = (int*)(w + 256);              // 8192 ints
  float* assign_w     = (float*)(w + 256 + 32768);    // 8192 floats
  size_t off = 256 + 32768 + 32768;
  __hip_bfloat16* xbf = (__hip_bfloat16*)(w + off); off += (size_t)NTOK * DDIM * 2;   // 4 MB
  __hip_bfloat16* Xg  = (__hip_bfloat16*)(w + off); off += (size_t)NEXP * CAP * DDIM * 2; // 16 MB
  __hip_bfloat16* Hs  = (__hip_bfloat16*)(w + off); off += (size_t)NTOK * HSH * 2;    // 8 MB
  __hip_bfloat16* H   = (__hip_bfloat16*)(w + off); off += (size_t)NEXP * CAP * HDIM * 2; // 64 MB

  hipMemsetAsync(counts, 0, 256, stream);
  hipMemsetAsync(assign_token, 0xFF, 32768, stream);          // -1 sentinel
  hipMemsetAsync(d_out, 0, (size_t)out_size * 4, stream);     // split-K accumulates

  gate_kernel<<<NTOK / 4, 256, 0, stream>>>(x, gate_w, bias, xbf, Xg,
                                            counts, assign_token, assign_w);

  // shared FC1: xbf[2048x1024] @ shared_w1[1024x2048] -> silu -> Hs (bf16)
  gemm_kernel<0><<<dim3(HSH / BN, NTOK / BM, 1), 256, 0, stream>>>(
      xbf, (size_t)BM * DDIM, shared_w1, 0,
      DDIM, DDIM, HSH, HSH, nullptr, Hs, nullptr, nullptr);

  // expert FC1: Xg[e] @ expert_w1[e][1024x4096] -> silu -> H (bf16)
  gemm_kernel<0><<<dim3(HDIM / BN, NEXP, 1), 256, 0, stream>>>(
      Xg, (size_t)CAP * DDIM, expert_w1, (size_t)DDIM * HDIM,
      DDIM, DDIM, HDIM, HDIM, nullptr, H, nullptr, nullptr);

  // shared FC2: Hs[2048x2048] @ shared_w2[2048x1024] -> atomicAdd out (split-K 4)
  gemm_kernel<2><<<dim3(DDIM / BN, NTOK / BM, 4), 256, 0, stream>>>(
      Hs, (size_t)BM * HSH, shared_w2, 0,
      HSH, HSH / 4, DDIM, DDIM, out, nullptr, nullptr, nullptr);

  // expert FC2: H[e] @ expert_w2[e][4096x1024] -> w * atomicAdd out (split-K 2)
  gemm_kernel<1><<<dim3(DDIM / BN, NEXP, 2), 256, 0, stream>>>(
      H, (size_t)CAP * HDIM, expert_w2, (size_t)HDIM * DDIM,
      HDIM, HDIM / 2, DDIM, DDIM, out, nullptr, assign_token, assign_w);
}